// Round 11
// baseline (109.341 us; speedup 1.0000x reference)
//
#include <hip/hip_runtime.h>
#include <math.h>

// Problem constants
#define DIM   256
#define NST   256
#define LSEQ  512
#define BAT   2
#define DTSZ  64
#define PCOLS 576
#define NROWS 1024

typedef float    f32x4 __attribute__((ext_vector_type(4)));
typedef unsigned u32x4 __attribute__((ext_vector_type(4)));

constexpr float LOG2E = 1.4426950408889634f;

__device__ __forceinline__ float fexp2(float v) {
#if __has_builtin(__builtin_amdgcn_exp2f)
    return __builtin_amdgcn_exp2f(v);
#else
    return exp2f(v);
#endif
}

__device__ __forceinline__ float softplusf(float v) {
    return (v > 20.f) ? v : log1pf(__expf(v));
}

// LDS-only barrier: waits lgkmcnt(0) but leaves global (vmcnt) loads in flight.
__device__ __forceinline__ void barrier_lds_only() {
    __builtin_amdgcn_s_waitcnt(0xC07F);   // vmcnt=63, expcnt=7, lgkmcnt=0
    __builtin_amdgcn_s_barrier();
}

// Pack (beta, gamma) as bf16x2 in one dword: beta lo16, gamma hi16. RNE.
__device__ __forceinline__ unsigned pack_bg(float be, float ga) {
    unsigned ub = __float_as_uint(be);
    unsigned ug = __float_as_uint(ga);
    ub = (ub + 0x7fffu + ((ub >> 16) & 1u)) >> 16;
    ug = (ug + 0x7fffu + ((ug >> 16) & 1u)) & 0xffff0000u;
    return ub | ug;
}

// fp32 -> bf16 (RNE) as u16.
__device__ __forceinline__ unsigned short rne16(float f) {
    unsigned u = __float_as_uint(f);
    return (unsigned short)((u + 0x7fffu + ((u >> 16) & 1u)) >> 16);
}

// v_cvt_pk_bf16_f32: two fp32 -> packed bf16x2 (lo = src0, hi = src1), 1 instr.
// (harness-verified R4)
__device__ __forceinline__ unsigned cvtpk(float lo, float hi) {
    unsigned r;
    asm("v_cvt_pk_bf16_f32 %0, %1, %2" : "=v"(r) : "v"(lo), "v"(hi));
    return r;
}

// MFMA via inline asm. D = A(16x32 bf16) * B(32x16 bf16) + C.
// A: row=lane&15, k=(lane>>4)*8+i.  B: col=lane&15, k=(lane>>4)*8+i.
// C/D: col=lane&15, row=(lane>>4)*4+r.   (harness-verified R4)
__device__ __forceinline__ f32x4 mfma16(u32x4 a, u32x4 b, f32x4 c) {
    asm("v_mfma_f32_16x16x32_bf16 %0, %1, %2, %0" : "+v"(c) : "v"(a), "v"(b));
    return c;
}

// ---------------- proj_mfma: EXACT R8 version (passing, betgam4 row-quads).
__global__ __launch_bounds__(256, 2) void proj_mfma(
    const float* __restrict__ x, const float* __restrict__ W_in,
    u32x4* __restrict__ betgam4,       // [NROWS/4, NST] row-quads
    float* __restrict__ draw)          // [NROWS, DTSZ] fp32 dt_raw
{
    __shared__ unsigned short Bt[64][264];   // 33792 B
    const int tid  = threadIdx.x;
    const int lane = tid & 63;
    const int mt   = blockIdx.x / 9;
    const int role = blockIdx.x % 9;

    const int base0 = (role < 8) ? (64  + 32 * role) : 0;
    const int base1 = (role < 8) ? (320 + 32 * role) : 32;
    {
        const int cs = tid & 15;          // col-pair index (0..15)
        const int kq = tid >> 4;          // 0..15
        #pragma unroll 8
        for (int p = 0; p < 16; ++p) {
            const int k = p * 16 + kq;
            const float2 v0 = *(const float2*)&W_in[k * PCOLS + base0 + 2 * cs];
            const float2 v1 = *(const float2*)&W_in[k * PCOLS + base1 + 2 * cs];
            Bt[2 * cs][k]          = rne16(v0.x);
            Bt[2 * cs + 1][k]      = rne16(v0.y);
            Bt[32 + 2 * cs][k]     = rne16(v1.x);
            Bt[32 + 2 * cs + 1][k] = rne16(v1.y);
        }
    }
    __syncthreads();

    const int w    = tid >> 6;
    const int wm   = w >> 1, wn = w & 1;
    const int row  = mt * 32 + wm * 16 + (lane & 15);
    const int koff = (lane >> 4) * 8;
    const float* xp = x + row * DIM + koff;
    const unsigned short* bp1 = &Bt[16 * wn + (lane & 15)][koff];
    const unsigned short* bp2 = &Bt[32 + 16 * wn + (lane & 15)][koff];

    f32x4 acc1 = {0.f, 0.f, 0.f, 0.f};
    f32x4 acc2 = {0.f, 0.f, 0.f, 0.f};
    #pragma unroll
    for (int kk = 0; kk < 8; ++kk) {     // K = 8 x 32
        const float4 xa = *(const float4*)(xp + kk * 32);
        const float4 xb = *(const float4*)(xp + kk * 32 + 4);
        u32x4 a;
        a.x = cvtpk(xa.x, xa.y);
        a.y = cvtpk(xa.z, xa.w);
        a.z = cvtpk(xb.x, xb.y);
        a.w = cvtpk(xb.z, xb.w);
        const u32x4 b1 = *(const u32x4*)(bp1 + kk * 32);
        const u32x4 b2 = *(const u32x4*)(bp2 + kk * 32);
        acc1 = mfma16(a, b1, acc1);
        acc2 = mfma16(a, b2, acc2);
    }

    const int rowbase = mt * 32 + wm * 16 + (lane >> 4) * 4;   // %4 == 0
    if (role < 8) {
        const int n = 32 * role + 16 * wn + (lane & 15);
        u32x4 st;
        st.x = pack_bg(acc1[0], acc2[0]);
        st.y = pack_bg(acc1[1], acc2[1]);
        st.z = pack_bg(acc1[2], acc2[2]);
        st.w = pack_bg(acc1[3], acc2[3]);
        betgam4[(rowbase >> 2) * NST + n] = st;
    } else {
        const int c1 = 16 * wn + (lane & 15);
        #pragma unroll
        for (int r = 0; r < 4; ++r) {
            draw[(rowbase + r) * DTSZ + c1]      = acc1[r];
            draw[(rowbase + r) * DTSZ + 32 + c1] = acc2[r];
        }
    }
}

// ---------------- scan1p: R8 skeleton (betgam4 loads, dbuf, 40.7us) with the
// part[] system halved in LDS bytes: partials stored bf16-PAIR-packed and
// TRANSPOSED. partp[buf][n][rp] (u32, stride 17 dwords) holds group-rows
// (2rp, 2rp+1) for state n: lo16 = row 2rp (cvtpk src0), hi16 = row 2rp+1.
// Writes: 4 b32/window (was 8; bytes halved; bank = n*17+col -> 2-way max,
// free). Reduce: 16 reads serve 2 rows each (was 32), 4-level shfl over seg.
__global__ __launch_bounds__(256, 2) void scan1p(
    const float* __restrict__ x,            // [NROWS, DIM]
    const float* __restrict__ alpha_log,    // [DIM, NST]
    const float* __restrict__ delta,        // [DIM]
    const u32x4* __restrict__ betgam4,      // [NROWS/4, NST] row-quads
    const float* __restrict__ draw,         // [NROWS, DTSZ]
    const float* __restrict__ W_dt,         // [DTSZ, DIM]
    const float* __restrict__ b_dt,         // [DIM]
    float* __restrict__ out)                // [NROWS, DIM]
{
    __shared__ unsigned partp[2][NST][17];  // 34816 B double-buffered
    __shared__ float dts[LSEQ], dxs[LSEQ], xcol[LSEQ];   // 3 x 2 KB
    __shared__ float wdt[DTSZ];             // 256 B
    const int n = threadIdx.x;
    // XCD swizzle (R10-verified): XCDs 0-3 -> b=0, 4-7 -> b=1.
    const int xcd  = blockIdx.x & 7;
    const int slot = blockIdx.x >> 3;       // 0..63
    const int b = xcd >> 2;
    const int d = slot * 4 + (xcd & 3);
    const int rb  = b * LSEQ;
    const int rbq = rb >> 2;                // quad-row base (= b*128)

    if (n < DTSZ) wdt[n] = W_dt[n * DIM + d];
    #pragma unroll
    for (int it = 0; it < 2; ++it) {
        const int l = n + it * 256;
        xcol[l] = x[(rb + l) * DIM + d];
    }
    const float aln = -__expf(alpha_log[d * NST + n]) * LOG2E;
    const float dv  = delta[d];
    const float bdv = b_dt[d];

    // 6-window betgam prefetch (12 dwordx4 loads), in flight through the
    // dt prologue.  (R8-verified)
    u32x4 bg[8][2];                         // 8-slot rotation of row-quads
    #pragma unroll
    for (int pw = 0; pw < 6; ++pw) {
        #pragma unroll
        for (int h = 0; h < 2; ++h)
            bg[pw][h] = betgam4[(rbq + pw * 2 + h) * NST + n];
    }

    barrier_lds_only();                     // wdt/xcol visible; vmcnt untouched

    // Fused dt GEMM: dts[l] = softplus(draw[rb+l,:] . wdt + b_dt[d])
    #pragma unroll
    for (int it = 0; it < 2; ++it) {
        const int l = n + it * 256;
        const float4* dr = (const float4*)&draw[(rb + l) * DTSZ];
        float acc = bdv;
        #pragma unroll
        for (int c = 0; c < 16; ++c) {
            const float4 v  = dr[c];
            const float4 wv = *(const float4*)&wdt[c * 4];
            acc = fmaf(v.x, wv.x, acc);
            acc = fmaf(v.y, wv.y, acc);
            acc = fmaf(v.z, wv.z, acc);
            acc = fmaf(v.w, wv.w, acc);
        }
        const float sp = softplusf(acc);
        dts[l] = sp;
        dxs[l] = sp * xcol[l];
    }
    __syncthreads();                        // dts/dxs ready

    float s = 0.f;
    #pragma unroll 8
    for (int w = 0; w < 64; ++w) {
        const int cur = w & 7;              // static under unroll-8
        const int pf  = (w + 6) & 7;
        const int bufsel = (w >> 2) & 1;    // static: group double-buffer
        if (w + 6 < 64) {                   // issue window w+6 while computing w
            bg[pf][0] = betgam4[(rbq + (w + 6) * 2)     * NST + n];
            bg[pf][1] = betgam4[(rbq + (w + 6) * 2 + 1) * NST + n];
        }
        float4 dta = *(const float4*)&dts[w * 8];
        float4 dtb = *(const float4*)&dts[w * 8 + 4];
        float4 dxa = *(const float4*)&dxs[w * 8];
        float4 dxb = *(const float4*)&dxs[w * 8 + 4];
        const float dtw[8] = {dta.x, dta.y, dta.z, dta.w, dtb.x, dtb.y, dtb.z, dtb.w};
        const float dxw[8] = {dxa.x, dxa.y, dxa.z, dxa.w, dxb.x, dxb.y, dxb.z, dxb.w};

        float vv[8];                        // static-indexed (unrolled)
        #pragma unroll
        for (int t = 0; t < 8; ++t) {       // static t: bg const-indexed
            const unsigned u = bg[cur][t >> 2][t & 3];
            const float be = __uint_as_float(u << 16);
            const float ga = __uint_as_float(u & 0xffff0000u);
            float a = fexp2(dtw[t] * aln);
            s = fmaf(a, s, dxw[t] * be);
            vv[t] = s * ga;
        }
        const int rpbase = (w & 3) * 4;     // static: step-pair column base
        #pragma unroll
        for (int j = 0; j < 4; ++j)         // group-rows (2rp, 2rp+1)
            partp[bufsel][n][rpbase + j] = cvtpk(vv[2 * j], vv[2 * j + 1]);

        if ((w & 3) == 3) {                 // every 32 steps: reduce 32 rows
            barrier_lds_only();             // writes complete; WAR fence (dbuf)
            const int tp  = n >> 4;         // row-pair 0..15 -> rows 2tp,2tp+1
            const int seg = n & 15;         // 16 threads per row-pair
            float s0 = 0.f, s1 = 0.f;
            #pragma unroll
            for (int k = 0; k < 16; ++k) {  // 16 dwords cover 16 n, 2 rows each
                const int nn = seg * 16 + ((k + seg) & 15);   // rotation spread
                const unsigned u = partp[bufsel][nn][tp];
                s0 += __uint_as_float(u << 16);          // row 2tp
                s1 += __uint_as_float(u & 0xffff0000u);  // row 2tp+1
            }
            s0 += __shfl_xor(s0, 1);  s1 += __shfl_xor(s1, 1);
            s0 += __shfl_xor(s0, 2);  s1 += __shfl_xor(s1, 2);
            s0 += __shfl_xor(s0, 4);  s1 += __shfl_xor(s1, 4);
            s0 += __shfl_xor(s0, 8);  s1 += __shfl_xor(s1, 8);
            if (seg == 0) {
                const int l0 = (w >> 2) * 32 + 2 * tp;
                out[(rb + l0)     * DIM + d] = s0 + xcol[l0]     * dv;
                out[(rb + l0 + 1) * DIM + d] = s1 + xcol[l0 + 1] * dv;
            }
            // no trailing barrier: next group writes the OTHER buffer
        }
    }
}

extern "C" void kernel_launch(void* const* d_in, const int* in_sizes, int n_in,
                              void* d_out, int out_size, void* d_ws, size_t ws_size,
                              hipStream_t stream) {
    const float* x         = (const float*)d_in[0];
    const float* W_in      = (const float*)d_in[1];
    const float* W_dt      = (const float*)d_in[2];
    const float* b_dt      = (const float*)d_in[3];
    const float* alpha_log = (const float*)d_in[4];
    const float* delta     = (const float*)d_in[5];
    float* out = (float*)d_out;

    // Workspace: betgam4 1MB | draw 256KB
    u32x4* betgam4 = (u32x4*)d_ws;
    float* draw    = (float*)(betgam4 + (NROWS / 4) * NST);

    proj_mfma<<<32 * 9, 256, 0, stream>>>(x, W_in, betgam4, draw);
    scan1p<<<BAT * DIM, 256, 0, stream>>>(x, alpha_log, delta, betgam4,
                                          draw, W_dt, b_dt, out);
}

// Round 12
// 106.327 us; speedup vs baseline: 1.0283x; 1.0283x over previous
//
#include <hip/hip_runtime.h>
#include <math.h>

// Problem constants
#define DIM   256
#define NST   256
#define LSEQ  512
#define BAT   2
#define DTSZ  64
#define PCOLS 576
#define NROWS 1024

typedef float    f32x4 __attribute__((ext_vector_type(4)));
typedef unsigned u32x4 __attribute__((ext_vector_type(4)));

constexpr float LOG2E = 1.4426950408889634f;

__device__ __forceinline__ float fexp2(float v) {
#if __has_builtin(__builtin_amdgcn_exp2f)
    return __builtin_amdgcn_exp2f(v);
#else
    return exp2f(v);
#endif
}

__device__ __forceinline__ float softplusf(float v) {
    return (v > 20.f) ? v : log1pf(__expf(v));
}

// LDS-only barrier: waits lgkmcnt(0) but leaves global (vmcnt) loads in flight.
__device__ __forceinline__ void barrier_lds_only() {
    __builtin_amdgcn_s_waitcnt(0xC07F);   // vmcnt=63, expcnt=7, lgkmcnt=0
    __builtin_amdgcn_s_barrier();
}

// Pack (beta, gamma) as bf16x2 in one dword: beta lo16, gamma hi16. RNE.
__device__ __forceinline__ unsigned pack_bg(float be, float ga) {
    unsigned ub = __float_as_uint(be);
    unsigned ug = __float_as_uint(ga);
    ub = (ub + 0x7fffu + ((ub >> 16) & 1u)) >> 16;
    ug = (ug + 0x7fffu + ((ug >> 16) & 1u)) & 0xffff0000u;
    return ub | ug;
}

// fp32 -> bf16 (RNE) as u16.
__device__ __forceinline__ unsigned short rne16(float f) {
    unsigned u = __float_as_uint(f);
    return (unsigned short)((u + 0x7fffu + ((u >> 16) & 1u)) >> 16);
}

// v_cvt_pk_bf16_f32: two fp32 -> packed bf16x2 (lo = src0, hi = src1), 1 instr.
// (harness-verified R4)
__device__ __forceinline__ unsigned cvtpk(float lo, float hi) {
    unsigned r;
    asm("v_cvt_pk_bf16_f32 %0, %1, %2" : "=v"(r) : "v"(lo), "v"(hi));
    return r;
}

// MFMA via inline asm. D = A(16x32 bf16) * B(32x16 bf16) + C.
// A: row=lane&15, k=(lane>>4)*8+i.  B: col=lane&15, k=(lane>>4)*8+i.
// C/D: col=lane&15, row=(lane>>4)*4+r.   (harness-verified R4)
__device__ __forceinline__ f32x4 mfma16(u32x4 a, u32x4 b, f32x4 c) {
    asm("v_mfma_f32_16x16x32_bf16 %0, %1, %2, %0" : "+v"(c) : "v"(a), "v"(b));
    return c;
}

// ---------------- proj_mfma: x@W_in via bf16 MFMA (R4-verified core, R7
// quad-store, R8 float2 stage). Best-measured passing version (R8).
__global__ __launch_bounds__(256, 2) void proj_mfma(
    const float* __restrict__ x, const float* __restrict__ W_in,
    u32x4* __restrict__ betgam4,       // [NROWS/4, NST] row-quads
    float* __restrict__ draw)          // [NROWS, DTSZ] fp32 dt_raw
{
    __shared__ unsigned short Bt[64][264];   // 33792 B
    const int tid  = threadIdx.x;
    const int lane = tid & 63;
    const int mt   = blockIdx.x / 9;
    const int role = blockIdx.x % 9;

    const int base0 = (role < 8) ? (64  + 32 * role) : 0;
    const int base1 = (role < 8) ? (320 + 32 * role) : 32;
    {
        const int cs = tid & 15;          // col-pair index (0..15)
        const int kq = tid >> 4;          // 0..15
        #pragma unroll 8
        for (int p = 0; p < 16; ++p) {
            const int k = p * 16 + kq;
            const float2 v0 = *(const float2*)&W_in[k * PCOLS + base0 + 2 * cs];
            const float2 v1 = *(const float2*)&W_in[k * PCOLS + base1 + 2 * cs];
            Bt[2 * cs][k]          = rne16(v0.x);
            Bt[2 * cs + 1][k]      = rne16(v0.y);
            Bt[32 + 2 * cs][k]     = rne16(v1.x);
            Bt[32 + 2 * cs + 1][k] = rne16(v1.y);
        }
    }
    __syncthreads();

    const int w    = tid >> 6;
    const int wm   = w >> 1, wn = w & 1;
    const int row  = mt * 32 + wm * 16 + (lane & 15);
    const int koff = (lane >> 4) * 8;
    const float* xp = x + row * DIM + koff;
    const unsigned short* bp1 = &Bt[16 * wn + (lane & 15)][koff];
    const unsigned short* bp2 = &Bt[32 + 16 * wn + (lane & 15)][koff];

    f32x4 acc1 = {0.f, 0.f, 0.f, 0.f};
    f32x4 acc2 = {0.f, 0.f, 0.f, 0.f};
    #pragma unroll
    for (int kk = 0; kk < 8; ++kk) {     // K = 8 x 32
        const float4 xa = *(const float4*)(xp + kk * 32);
        const float4 xb = *(const float4*)(xp + kk * 32 + 4);
        u32x4 a;
        a.x = cvtpk(xa.x, xa.y);
        a.y = cvtpk(xa.z, xa.w);
        a.z = cvtpk(xb.x, xb.y);
        a.w = cvtpk(xb.z, xb.w);
        const u32x4 b1 = *(const u32x4*)(bp1 + kk * 32);
        const u32x4 b2 = *(const u32x4*)(bp2 + kk * 32);
        acc1 = mfma16(a, b1, acc1);
        acc2 = mfma16(a, b2, acc2);
    }

    const int rowbase = mt * 32 + wm * 16 + (lane >> 4) * 4;   // %4 == 0
    if (role < 8) {
        const int n = 32 * role + 16 * wn + (lane & 15);
        u32x4 st;
        st.x = pack_bg(acc1[0], acc2[0]);
        st.y = pack_bg(acc1[1], acc2[1]);
        st.z = pack_bg(acc1[2], acc2[2]);
        st.w = pack_bg(acc1[3], acc2[3]);
        betgam4[(rowbase >> 2) * NST + n] = st;
    } else {
        const int c1 = 16 * wn + (lane & 15);
        #pragma unroll
        for (int r = 0; r < 4; ++r) {
            draw[(rowbase + r) * DTSZ + c1]      = acc1[r];
            draw[(rowbase + r) * DTSZ + 32 + c1] = acc2[r];
        }
    }
}

// ---------------- scan1p: best-measured passing version (R8, 40.7us).
// Single-pass serial scan; betgam row-quad dwordx4 loads (R7); part[] reduce
// double-buffered with one barrier per reduce (R8); measured-0-conflict
// reduce read rotation; 6-window prefetch hidden under the dt prologue.
__global__ __launch_bounds__(256, 2) void scan1p(
    const float* __restrict__ x,            // [NROWS, DIM]
    const float* __restrict__ alpha_log,    // [DIM, NST]
    const float* __restrict__ delta,        // [DIM]
    const u32x4* __restrict__ betgam4,      // [NROWS/4, NST] row-quads
    const float* __restrict__ draw,         // [NROWS, DTSZ]
    const float* __restrict__ W_dt,         // [DTSZ, DIM]
    const float* __restrict__ b_dt,         // [DIM]
    float* __restrict__ out)                // [NROWS, DIM]
{
    __shared__ float part[2][32][NST];      // 64 KB double-buffered
    __shared__ float dts[LSEQ], dxs[LSEQ], xcol[LSEQ];   // 3 x 2 KB
    __shared__ float wdt[DTSZ];             // 256 B
    const int n = threadIdx.x;
    // XCD swizzle (R10-verified): XCDs 0-3 -> b=0, 4-7 -> b=1.
    const int xcd  = blockIdx.x & 7;
    const int slot = blockIdx.x >> 3;       // 0..63
    const int b = xcd >> 2;
    const int d = slot * 4 + (xcd & 3);
    const int rb  = b * LSEQ;
    const int rbq = rb >> 2;                // quad-row base (= b*128)

    if (n < DTSZ) wdt[n] = W_dt[n * DIM + d];
    #pragma unroll
    for (int it = 0; it < 2; ++it) {
        const int l = n + it * 256;
        xcol[l] = x[(rb + l) * DIM + d];
    }
    const float aln = -__expf(alpha_log[d * NST + n]) * LOG2E;
    const float dv  = delta[d];
    const float bdv = b_dt[d];

    // 6-window betgam prefetch (12 dwordx4 loads), in flight through the
    // dt prologue.
    u32x4 bg[8][2];                         // 8-slot rotation of row-quads
    #pragma unroll
    for (int pw = 0; pw < 6; ++pw) {
        #pragma unroll
        for (int h = 0; h < 2; ++h)
            bg[pw][h] = betgam4[(rbq + pw * 2 + h) * NST + n];
    }

    barrier_lds_only();                     // wdt/xcol visible; vmcnt untouched

    // Fused dt GEMM: dts[l] = softplus(draw[rb+l,:] . wdt + b_dt[d])
    #pragma unroll
    for (int it = 0; it < 2; ++it) {
        const int l = n + it * 256;
        const float4* dr = (const float4*)&draw[(rb + l) * DTSZ];
        float acc = bdv;
        #pragma unroll
        for (int c = 0; c < 16; ++c) {
            const float4 v  = dr[c];
            const float4 wv = *(const float4*)&wdt[c * 4];
            acc = fmaf(v.x, wv.x, acc);
            acc = fmaf(v.y, wv.y, acc);
            acc = fmaf(v.z, wv.z, acc);
            acc = fmaf(v.w, wv.w, acc);
        }
        const float sp = softplusf(acc);
        dts[l] = sp;
        dxs[l] = sp * xcol[l];
    }
    __syncthreads();                        // dts/dxs ready

    float s = 0.f;
    #pragma unroll 8
    for (int w = 0; w < 64; ++w) {
        const int cur = w & 7;              // static under unroll-8
        const int pf  = (w + 6) & 7;
        const int bufsel = (w >> 2) & 1;    // static: group double-buffer
        if (w + 6 < 64) {                   // issue window w+6 while computing w
            bg[pf][0] = betgam4[(rbq + (w + 6) * 2)     * NST + n];
            bg[pf][1] = betgam4[(rbq + (w + 6) * 2 + 1) * NST + n];
        }
        float4 dta = *(const float4*)&dts[w * 8];
        float4 dtb = *(const float4*)&dts[w * 8 + 4];
        float4 dxa = *(const float4*)&dxs[w * 8];
        float4 dxb = *(const float4*)&dxs[w * 8 + 4];
        const float dtw[8] = {dta.x, dta.y, dta.z, dta.w, dtb.x, dtb.y, dtb.z, dtb.w};
        const float dxw[8] = {dxa.x, dxa.y, dxa.z, dxa.w, dxb.x, dxb.y, dxb.z, dxb.w};

        const int prow = (w & 3) * 8;
        #pragma unroll
        for (int t = 0; t < 8; ++t) {       // static t: bg const-indexed
            const unsigned u = bg[cur][t >> 2][t & 3];
            const float be = __uint_as_float(u << 16);
            const float ga = __uint_as_float(u & 0xffff0000u);
            float a = fexp2(dtw[t] * aln);
            s = fmaf(a, s, dxw[t] * be);
            part[bufsel][prow + t][n] = s * ga;   // 2-way bank alias: free
        }

        if ((w & 3) == 3) {                 // every 32 steps: reduce 32 rows x 256
            barrier_lds_only();             // writes complete; WAR fence for g+2
            const int trow = n >> 3, seg = n & 7;
            float sum = 0.f;
            #pragma unroll
            for (int k = 0; k < 32; ++k)
                sum += part[bufsel][trow][seg * 32 + ((k + n) & 31)];  // 0-conflict
            sum += __shfl_xor(sum, 1);
            sum += __shfl_xor(sum, 2);
            sum += __shfl_xor(sum, 4);
            if (seg == 0) {
                const int l = (w >> 2) * 32 + trow;
                out[(rb + l) * DIM + d] = sum + xcol[l] * dv;
            }
            // no trailing barrier: next group writes the OTHER buffer
        }
    }
}

extern "C" void kernel_launch(void* const* d_in, const int* in_sizes, int n_in,
                              void* d_out, int out_size, void* d_ws, size_t ws_size,
                              hipStream_t stream) {
    const float* x         = (const float*)d_in[0];
    const float* W_in      = (const float*)d_in[1];
    const float* W_dt      = (const float*)d_in[2];
    const float* b_dt      = (const float*)d_in[3];
    const float* alpha_log = (const float*)d_in[4];
    const float* delta     = (const float*)d_in[5];
    float* out = (float*)d_out;

    // Workspace: betgam4 1MB | draw 256KB
    u32x4* betgam4 = (u32x4*)d_ws;
    float* draw    = (float*)(betgam4 + (NROWS / 4) * NST);

    proj_mfma<<<32 * 9, 256, 0, stream>>>(x, W_in, betgam4, draw);
    scan1p<<<BAT * DIM, 256, 0, stream>>>(x, alpha_log, delta, betgam4,
                                          draw, W_dt, b_dt, out);
}

// Round 13
// 104.837 us; speedup vs baseline: 1.0430x; 1.0142x over previous
//
#include <hip/hip_runtime.h>
#include <math.h>

// Problem constants
#define DIM   256
#define NST   256
#define LSEQ  512
#define BAT   2
#define DTSZ  64
#define PCOLS 576
#define NROWS 1024

typedef float    f32x4 __attribute__((ext_vector_type(4)));
typedef unsigned u32x4 __attribute__((ext_vector_type(4)));

constexpr float LOG2E = 1.4426950408889634f;

__device__ __forceinline__ float fexp2(float v) {
#if __has_builtin(__builtin_amdgcn_exp2f)
    return __builtin_amdgcn_exp2f(v);
#else
    return exp2f(v);
#endif
}

__device__ __forceinline__ float softplusf(float v) {
    return (v > 20.f) ? v : log1pf(__expf(v));
}

// LDS-only barrier: waits lgkmcnt(0) but leaves global (vmcnt) loads in flight.
__device__ __forceinline__ void barrier_lds_only() {
    __builtin_amdgcn_s_waitcnt(0xC07F);   // vmcnt=63, expcnt=7, lgkmcnt=0
    __builtin_amdgcn_s_barrier();
}

// Pack (beta, gamma) as bf16x2 in one dword: beta lo16, gamma hi16. RNE.
__device__ __forceinline__ unsigned pack_bg(float be, float ga) {
    unsigned ub = __float_as_uint(be);
    unsigned ug = __float_as_uint(ga);
    ub = (ub + 0x7fffu + ((ub >> 16) & 1u)) >> 16;
    ug = (ug + 0x7fffu + ((ug >> 16) & 1u)) & 0xffff0000u;
    return ub | ug;
}

// fp32 -> bf16 (RNE) as u16.
__device__ __forceinline__ unsigned short rne16(float f) {
    unsigned u = __float_as_uint(f);
    return (unsigned short)((u + 0x7fffu + ((u >> 16) & 1u)) >> 16);
}

// v_cvt_pk_bf16_f32: two fp32 -> packed bf16x2 (lo = src0, hi = src1), 1 instr.
// (harness-verified R4)
__device__ __forceinline__ unsigned cvtpk(float lo, float hi) {
    unsigned r;
    asm("v_cvt_pk_bf16_f32 %0, %1, %2" : "=v"(r) : "v"(lo), "v"(hi));
    return r;
}

// MFMA via inline asm. D = A(16x32 bf16) * B(32x16 bf16) + C.
// A: row=lane&15, k=(lane>>4)*8+i.  B: col=lane&15, k=(lane>>4)*8+i.
// C/D: col=lane&15, row=(lane>>4)*4+r.   (harness-verified R4)
__device__ __forceinline__ f32x4 mfma16(u32x4 a, u32x4 b, f32x4 c) {
    asm("v_mfma_f32_16x16x32_bf16 %0, %1, %2, %0" : "+v"(c) : "v"(a), "v"(b));
    return c;
}

// ---------------- proj_mfma v3: grid = EXACTLY 256 blocks (1/CU, no
// straggler tail — at 288 blocks, 32 CUs ran 2 blocks serially = 2x critical
// path with the machine idle). Role 8's dt work is folded into all 8 roles:
// block (mt, role) computes its verified 64-col betgam pair PLUS dt cols
// 8*role..8*role+7 (staged as Bt rows 64..71; wn=0 waves run 1 extra MFMA
// per kk). dt B-fragment lanes 8..15 read unstaged LDS rows 72..79 —
// garbage, but MFMA output col c depends only on B col c, and those outputs
// are never stored. draw partition: rows mt*32..+31 x cols 8r..8r+7, exact.
__global__ __launch_bounds__(256, 2) void proj_mfma(
    const float* __restrict__ x, const float* __restrict__ W_in,
    u32x4* __restrict__ betgam4,       // [NROWS/4, NST] row-quads
    float* __restrict__ draw)          // [NROWS, DTSZ] fp32 dt_raw
{
    __shared__ unsigned short Bt[80][264];   // 42240 B (72..79 = unstaged pad)
    const int tid  = threadIdx.x;
    const int lane = tid & 63;
    const int mt   = blockIdx.x >> 3;        // 0..31 (row-tile)
    const int role = blockIdx.x & 7;         // 0..7

    // ---- stage betgam strips (R8-verified float2 pattern)
    const int base0 = 64  + 32 * role;
    const int base1 = 320 + 32 * role;
    {
        const int cs = tid & 15;          // col-pair index (0..15)
        const int kq = tid >> 4;          // 0..15
        #pragma unroll 8
        for (int p = 0; p < 16; ++p) {
            const int k = p * 16 + kq;
            const float2 v0 = *(const float2*)&W_in[k * PCOLS + base0 + 2 * cs];
            const float2 v1 = *(const float2*)&W_in[k * PCOLS + base1 + 2 * cs];
            Bt[2 * cs][k]          = rne16(v0.x);
            Bt[2 * cs + 1][k]      = rne16(v0.y);
            Bt[32 + 2 * cs][k]     = rne16(v1.x);
            Bt[32 + 2 * cs + 1][k] = rne16(v1.y);
        }
    }
    // ---- stage dt cols 8*role..8*role+7 -> Bt[64+c][k]
    {
        const int cs = tid & 3;           // col-pair (0..3)
        const int kq = tid >> 2;          // 0..63
        #pragma unroll
        for (int p = 0; p < 4; ++p) {
            const int k = p * 64 + kq;
            const float2 v = *(const float2*)&W_in[k * PCOLS + 8 * role + 2 * cs];
            Bt[64 + 2 * cs][k]     = rne16(v.x);
            Bt[64 + 2 * cs + 1][k] = rne16(v.y);
        }
    }
    __syncthreads();

    const int w    = tid >> 6;
    const int wm   = w >> 1, wn = w & 1;
    const int row  = mt * 32 + wm * 16 + (lane & 15);
    const int koff = (lane >> 4) * 8;
    const float* xp = x + row * DIM + koff;
    const unsigned short* bp1 = &Bt[16 * wn + (lane & 15)][koff];
    const unsigned short* bp2 = &Bt[32 + 16 * wn + (lane & 15)][koff];
    const unsigned short* bpd = &Bt[64 + (lane & 15)][koff];

    f32x4 acc1 = {0.f, 0.f, 0.f, 0.f};
    f32x4 acc2 = {0.f, 0.f, 0.f, 0.f};
    f32x4 accd = {0.f, 0.f, 0.f, 0.f};
    #pragma unroll
    for (int kk = 0; kk < 8; ++kk) {     // K = 8 x 32
        const float4 xa = *(const float4*)(xp + kk * 32);
        const float4 xb = *(const float4*)(xp + kk * 32 + 4);
        u32x4 a;
        a.x = cvtpk(xa.x, xa.y);
        a.y = cvtpk(xa.z, xa.w);
        a.z = cvtpk(xb.x, xb.y);
        a.w = cvtpk(xb.z, xb.w);
        const u32x4 b1 = *(const u32x4*)(bp1 + kk * 32);
        const u32x4 b2 = *(const u32x4*)(bp2 + kk * 32);
        acc1 = mfma16(a, b1, acc1);
        acc2 = mfma16(a, b2, acc2);
        if (wn == 0) {                    // wave-uniform: no divergence cost
            const u32x4 bd = *(const u32x4*)(bpd + kk * 32);
            accd = mfma16(a, bd, accd);
        }
    }

    const int rowbase = mt * 32 + wm * 16 + (lane >> 4) * 4;   // %4 == 0
    {
        const int n = 32 * role + 16 * wn + (lane & 15);
        u32x4 st;
        st.x = pack_bg(acc1[0], acc2[0]);
        st.y = pack_bg(acc1[1], acc2[1]);
        st.z = pack_bg(acc1[2], acc2[2]);
        st.w = pack_bg(acc1[3], acc2[3]);
        betgam4[(rowbase >> 2) * NST + n] = st;
    }
    if (wn == 0 && (lane & 15) < 8) {     // valid dt cols only
        const int c = 8 * role + (lane & 15);
        #pragma unroll
        for (int r = 0; r < 4; ++r)
            draw[(rowbase + r) * DTSZ + c] = accd[r];
    }
}

// ---------------- scan1p: best-measured passing version (R8, 40.7us x3).
// BYTE-IDENTICAL to R12.
__global__ __launch_bounds__(256, 2) void scan1p(
    const float* __restrict__ x,            // [NROWS, DIM]
    const float* __restrict__ alpha_log,    // [DIM, NST]
    const float* __restrict__ delta,        // [DIM]
    const u32x4* __restrict__ betgam4,      // [NROWS/4, NST] row-quads
    const float* __restrict__ draw,         // [NROWS, DTSZ]
    const float* __restrict__ W_dt,         // [DTSZ, DIM]
    const float* __restrict__ b_dt,         // [DIM]
    float* __restrict__ out)                // [NROWS, DIM]
{
    __shared__ float part[2][32][NST];      // 64 KB double-buffered
    __shared__ float dts[LSEQ], dxs[LSEQ], xcol[LSEQ];   // 3 x 2 KB
    __shared__ float wdt[DTSZ];             // 256 B
    const int n = threadIdx.x;
    // XCD swizzle (R10-verified): XCDs 0-3 -> b=0, 4-7 -> b=1.
    const int xcd  = blockIdx.x & 7;
    const int slot = blockIdx.x >> 3;       // 0..63
    const int b = xcd >> 2;
    const int d = slot * 4 + (xcd & 3);
    const int rb  = b * LSEQ;
    const int rbq = rb >> 2;                // quad-row base (= b*128)

    if (n < DTSZ) wdt[n] = W_dt[n * DIM + d];
    #pragma unroll
    for (int it = 0; it < 2; ++it) {
        const int l = n + it * 256;
        xcol[l] = x[(rb + l) * DIM + d];
    }
    const float aln = -__expf(alpha_log[d * NST + n]) * LOG2E;
    const float dv  = delta[d];
    const float bdv = b_dt[d];

    // 6-window betgam prefetch (12 dwordx4 loads), in flight through the
    // dt prologue.
    u32x4 bg[8][2];                         // 8-slot rotation of row-quads
    #pragma unroll
    for (int pw = 0; pw < 6; ++pw) {
        #pragma unroll
        for (int h = 0; h < 2; ++h)
            bg[pw][h] = betgam4[(rbq + pw * 2 + h) * NST + n];
    }

    barrier_lds_only();                     // wdt/xcol visible; vmcnt untouched

    // Fused dt GEMM: dts[l] = softplus(draw[rb+l,:] . wdt + b_dt[d])
    #pragma unroll
    for (int it = 0; it < 2; ++it) {
        const int l = n + it * 256;
        const float4* dr = (const float4*)&draw[(rb + l) * DTSZ];
        float acc = bdv;
        #pragma unroll
        for (int c = 0; c < 16; ++c) {
            const float4 v  = dr[c];
            const float4 wv = *(const float4*)&wdt[c * 4];
            acc = fmaf(v.x, wv.x, acc);
            acc = fmaf(v.y, wv.y, acc);
            acc = fmaf(v.z, wv.z, acc);
            acc = fmaf(v.w, wv.w, acc);
        }
        const float sp = softplusf(acc);
        dts[l] = sp;
        dxs[l] = sp * xcol[l];
    }
    __syncthreads();                        // dts/dxs ready

    float s = 0.f;
    #pragma unroll 8
    for (int w = 0; w < 64; ++w) {
        const int cur = w & 7;              // static under unroll-8
        const int pf  = (w + 6) & 7;
        const int bufsel = (w >> 2) & 1;    // static: group double-buffer
        if (w + 6 < 64) {                   // issue window w+6 while computing w
            bg[pf][0] = betgam4[(rbq + (w + 6) * 2)     * NST + n];
            bg[pf][1] = betgam4[(rbq + (w + 6) * 2 + 1) * NST + n];
        }
        float4 dta = *(const float4*)&dts[w * 8];
        float4 dtb = *(const float4*)&dts[w * 8 + 4];
        float4 dxa = *(const float4*)&dxs[w * 8];
        float4 dxb = *(const float4*)&dxs[w * 8 + 4];
        const float dtw[8] = {dta.x, dta.y, dta.z, dta.w, dtb.x, dtb.y, dtb.z, dtb.w};
        const float dxw[8] = {dxa.x, dxa.y, dxa.z, dxa.w, dxb.x, dxb.y, dxb.z, dxb.w};

        const int prow = (w & 3) * 8;
        #pragma unroll
        for (int t = 0; t < 8; ++t) {       // static t: bg const-indexed
            const unsigned u = bg[cur][t >> 2][t & 3];
            const float be = __uint_as_float(u << 16);
            const float ga = __uint_as_float(u & 0xffff0000u);
            float a = fexp2(dtw[t] * aln);
            s = fmaf(a, s, dxw[t] * be);
            part[bufsel][prow + t][n] = s * ga;   // 2-way bank alias: free
        }

        if ((w & 3) == 3) {                 // every 32 steps: reduce 32 rows x 256
            barrier_lds_only();             // writes complete; WAR fence for g+2
            const int trow = n >> 3, seg = n & 7;
            float sum = 0.f;
            #pragma unroll
            for (int k = 0; k < 32; ++k)
                sum += part[bufsel][trow][seg * 32 + ((k + n) & 31)];  // 0-conflict
            sum += __shfl_xor(sum, 1);
            sum += __shfl_xor(sum, 2);
            sum += __shfl_xor(sum, 4);
            if (seg == 0) {
                const int l = (w >> 2) * 32 + trow;
                out[(rb + l) * DIM + d] = sum + xcol[l] * dv;
            }
            // no trailing barrier: next group writes the OTHER buffer
        }
    }
}

extern "C" void kernel_launch(void* const* d_in, const int* in_sizes, int n_in,
                              void* d_out, int out_size, void* d_ws, size_t ws_size,
                              hipStream_t stream) {
    const float* x         = (const float*)d_in[0];
    const float* W_in      = (const float*)d_in[1];
    const float* W_dt      = (const float*)d_in[2];
    const float* b_dt      = (const float*)d_in[3];
    const float* alpha_log = (const float*)d_in[4];
    const float* delta     = (const float*)d_in[5];
    float* out = (float*)d_out;

    // Workspace: betgam4 1MB | draw 256KB
    u32x4* betgam4 = (u32x4*)d_ws;
    float* draw    = (float*)(betgam4 + (NROWS / 4) * NST);

    proj_mfma<<<256, 256, 0, stream>>>(x, W_in, betgam4, draw);
    scan1p<<<BAT * DIM, 256, 0, stream>>>(x, alpha_log, delta, betgam4,
                                          draw, W_dt, b_dt, out);
}